// Round 6
// baseline (281.610 us; speedup 1.0000x reference)
//
#include <hip/hip_runtime.h>
#include <hip/hip_bf16.h>

// Problem: B=8, S=1024, E=768, H=12, hd=64, R=16.
// Pipeline:
//   1. prep_w: W_eff = in_proj_w + lora_b@lora_a -> bf16 (2304x768); out_w -> bf16
//   2. GEMM1 (MODE 0): [Q|K|V] = x_f32 @ W_eff.T + bias (z=0,1,2), 2-phase dbuf,
//      A reg-staged f32->bf16 (fused cvt), B via global_load_lds. Writes
//      Q*0.125/K as [B,H,S,64] bf16, V transposed [B,H,64,S] bf16.
//   3. flash attention per (b,h): swapped-QK^T 32x32 MFMA, in-register softmax
//      (cvt_pk + permlane32_swap), defer-max, LDS-staged K/V (dbuf, XOR-swz),
//      XCD-locality remap. O -> [B,S,E] bf16
//   4. GEMM2 (MODE 1): out = O @ out_w.T + out_b -> f32 d_out, 2-phase dbuf.
// ws requirement: ~80.3 MB.

typedef __attribute__((ext_vector_type(4))) float f32x4;
typedef __attribute__((ext_vector_type(16))) float f32x16;
typedef __attribute__((ext_vector_type(8))) short bf16x8;
typedef __attribute__((ext_vector_type(4))) short s16x4;

#define E_DIM 768
#define NB 8
#define SEQ 1024
#define NH 12
#define HD 64
#define M_DIM (NB * SEQ)          // 8192
#define NKT (E_DIM / 64)          // 12 K-tiles

__device__ __forceinline__ short f2b(float f) {
    union { __hip_bfloat16 h; short s; } u;
    u.h = __float2bfloat16(f);
    return u.s;
}

__device__ __forceinline__ void async_cp16(const void* g, void* l) {
    __builtin_amdgcn_global_load_lds(
        (const __attribute__((address_space(1))) void*)g,
        (__attribute__((address_space(3))) void*)l, 16, 0, 0);
}

// ---------------- weight prep (W_eff + out_w cvt, one launch) ----------------
// blocks 0..1727: W_eff[r][c] = ipw[r][c] + sum_j lb[r][j]*la[j][c] -> bf16
// blocks 1728..2303: out_w f32 -> bf16
__global__ void prep_w_kernel(const float* __restrict__ ipw, const float* __restrict__ la,
                              const float* __restrict__ lb, const float* __restrict__ ow,
                              short* __restrict__ W, short* __restrict__ OW) {
    if (blockIdx.x < 1728) {
        int idx = blockIdx.x * 256 + threadIdx.x;       // 442368 total
        int r = idx / 192;
        int c = (idx % 192) * 4;
        float4 acc = *(const float4*)(ipw + (size_t)r * E_DIM + c);
        #pragma unroll
        for (int j = 0; j < 16; ++j) {
            float bb = lb[r * 16 + j];
            float4 aa = *(const float4*)(la + j * E_DIM + c);
            acc.x += bb * aa.x; acc.y += bb * aa.y; acc.z += bb * aa.z; acc.w += bb * aa.w;
        }
        s16x4 o; o[0] = f2b(acc.x); o[1] = f2b(acc.y); o[2] = f2b(acc.z); o[3] = f2b(acc.w);
        *(s16x4*)(W + (size_t)r * E_DIM + c) = o;
    } else {
        int i = ((blockIdx.x - 1728) * 256 + threadIdx.x) * 4;   // 589824 elems
        float4 a = *(const float4*)(ow + i);
        s16x4 o; o[0] = f2b(a.x); o[1] = f2b(a.y); o[2] = f2b(a.z); o[3] = f2b(a.w);
        *(s16x4*)(OW + i) = o;
    }
}

// ---------------- GEMM (C = A @ B^T + bias), 128x128 tile, BK=64, dbuf -------
// MODE 0: A = f32 q/k/v (reg-staged + fused bf16 cvt), QKV epilogue by z.
// MODE 1: A = bf16 (global_load_lds), f32 output.
template <int MODE>
__global__ __launch_bounds__(256) void gemm_bt(
    const float* __restrict__ Aq, const float* __restrict__ Ak,
    const float* __restrict__ Av, const short* __restrict__ Abf,
    const short* __restrict__ Ball, const float* __restrict__ biasAll,
    short* __restrict__ Qb, short* __restrict__ Kb, short* __restrict__ Vt,
    float* __restrict__ Cout) {
    __shared__ short sA[2][128 * 64];
    __shared__ short sB[2][128 * 64];
    const int z = blockIdx.z;
    const float* Afp = (MODE == 0) ? (z == 0 ? Aq : (z == 1 ? Ak : Av)) : nullptr;
    const short* Bp = Ball + (size_t)z * (size_t)(E_DIM * E_DIM);
    const float* bias = biasAll + z * E_DIM;
    const int tm = blockIdx.x * 128;
    const int tn = blockIdx.y * 128;
    const int t = threadIdx.x;
    const int lane = t & 63, wid = t >> 6;
    const int wr = wid >> 1, wc = wid & 1;
    const int lr = lane & 15, lg = lane >> 4;
    const int srow = lane >> 3;   // staging: row within 8-row chunk
    const int sgrp = lane & 7;    // staging: 16B group within row
    const int arow = t >> 1;      // MODE0 A staging: row 0..127
    const int ahalf = t & 1;      // MODE0 A staging: k-half (32 f32)

    float4 areg[8];

    // B tile staging: linear LDS dest, inverse-XOR-swizzled global source
    auto stageB = [&](short* dst, int k0) {
        #pragma unroll
        for (int is = 0; is < 4; ++is) {
            const int rbase = is * 32 + wid * 8;
            const int row = rbase + srow;
            const int gsw = (sgrp ^ (row & 7)) << 3;
            async_cp16(Bp + (size_t)(tn + row) * E_DIM + k0 + gsw, dst + rbase * 64);
        }
    };
    auto stageA16 = [&](short* dst, int k0) {
        #pragma unroll
        for (int is = 0; is < 4; ++is) {
            const int rbase = is * 32 + wid * 8;
            const int row = rbase + srow;
            const int gsw = (sgrp ^ (row & 7)) << 3;
            async_cp16(Abf + (size_t)(tm + row) * E_DIM + k0 + gsw, dst + rbase * 64);
        }
    };
    // MODE0: A f32 loads to regs (issue-early) ...
    auto loadA = [&](int k0) {
        const float* src = Afp + (size_t)(tm + arow) * E_DIM + k0 + ahalf * 32;
        #pragma unroll
        for (int g = 0; g < 8; ++g) areg[g] = ((const float4*)src)[g];
    };
    // ... cvt + swizzled ds_write (write-late)
    auto writeA = [&](short* dst) {
        #pragma unroll
        for (int g = 0; g < 4; ++g) {
            bf16x8 w;
            w[0] = f2b(areg[2 * g].x);     w[1] = f2b(areg[2 * g].y);
            w[2] = f2b(areg[2 * g].z);     w[3] = f2b(areg[2 * g].w);
            w[4] = f2b(areg[2 * g + 1].x); w[5] = f2b(areg[2 * g + 1].y);
            w[6] = f2b(areg[2 * g + 1].z); w[7] = f2b(areg[2 * g + 1].w);
            const int kgrp = ahalf * 4 + g;
            *(bf16x8*)&dst[arow * 64 + ((kgrp ^ (arow & 7)) << 3)] = w;
        }
    };

    f32x4 acc[4][4] = {};

    // prologue: fill buffer 0
    if (MODE == 0) { loadA(0); stageB(sB[0], 0); writeA(sA[0]); }
    else           { stageA16(sA[0], 0); stageB(sB[0], 0); }
    __syncthreads();

    int cur = 0;
    for (int kt = 0; kt < NKT; ++kt) {
        const int k0n = (kt + 1) * 64;
        const bool more = (kt + 1 < NKT);
        if (more) {
            stageB(sB[cur ^ 1], k0n);
            if (MODE == 0) loadA(k0n);
            else stageA16(sA[cur ^ 1], k0n);
        }
        #pragma unroll
        for (int kk = 0; kk < 2; ++kk) {
            bf16x8 af[4], bfr[4];
            const int kg = kk * 4 + lg;
            #pragma unroll
            for (int i = 0; i < 4; ++i) {
                const int row = wr * 64 + i * 16 + lr;
                af[i] = *(const bf16x8*)&sA[cur][row * 64 + ((kg ^ (row & 7)) << 3)];
            }
            #pragma unroll
            for (int j = 0; j < 4; ++j) {
                const int col = wc * 64 + j * 16 + lr;
                bfr[j] = *(const bf16x8*)&sB[cur][col * 64 + ((kg ^ (col & 7)) << 3)];
            }
            #pragma unroll
            for (int i = 0; i < 4; ++i)
                #pragma unroll
                for (int j = 0; j < 4; ++j)
                    acc[i][j] = __builtin_amdgcn_mfma_f32_16x16x32_bf16(
                        af[i], bfr[j], acc[i][j], 0, 0, 0);
        }
        if (MODE == 0 && more) writeA(sA[cur ^ 1]);
        __syncthreads();
        cur ^= 1;
    }

    // epilogue: C row m = lg*4+r within frag, col n = lr
    #pragma unroll
    for (int i = 0; i < 4; ++i) {
        const int m0 = tm + wr * 64 + i * 16 + lg * 4;
        const int b = m0 >> 10;
        const int s0 = m0 & 1023;
        #pragma unroll
        for (int j = 0; j < 4; ++j) {
            const int n = tn + wc * 64 + j * 16 + lr;
            const float bia = bias[n];
            f32x4 a = acc[i][j];
            if (MODE == 1) {
                #pragma unroll
                for (int r = 0; r < 4; ++r)
                    Cout[(size_t)(m0 + r) * E_DIM + n] = a[r] + bia;
            } else {
                const int h = n >> 6, d = n & 63;
                const int bh = b * NH + h;
                if (z == 0) {
                    #pragma unroll
                    for (int r = 0; r < 4; ++r)
                        Qb[((size_t)bh * SEQ + s0 + r) * HD + d] = f2b((a[r] + bia) * 0.125f);
                } else if (z == 1) {
                    #pragma unroll
                    for (int r = 0; r < 4; ++r)
                        Kb[((size_t)bh * SEQ + s0 + r) * HD + d] = f2b(a[r] + bia);
                } else {
                    s16x4 pk;
                    #pragma unroll
                    for (int r = 0; r < 4; ++r) pk[r] = f2b(a[r] + bia);
                    *(s16x4*)&Vt[((size_t)bh * HD + d) * SEQ + s0] = pk;   // V transposed
                }
            }
        }
    }
}

// ---------------- flash attention (swapped QK^T, in-register softmax) -------
// grid 768 1-D; XCD remap: bh = (p&7)*12 + (p>>3)/8, qblk = (p>>3)&7.
// Block = 4 waves; wave owns 32 q rows (q = q0 + lane&31; hi = lane>>5 splits
// the k/d fragment dims). K tile [32 k][64 d], V tile [64 d][32 k] in LDS,
// double-buffered, XOR-swizzled (linear dest + inverse-swz global source).
// S^T = mfma_32x32x16(K, Q^T): q = lane&31, k = (reg&3)+8*(reg>>2)+4*hi.
// P -> B-frag via v_cvt_pk_bf16_f32 + v_permlane32_swap_b32 (no LDS).
// O^T = mfma(V^T, P^T): per-lane scalar m/l; defer-max THR=8.
__global__ __launch_bounds__(256) void attn_kernel(
    const short* __restrict__ Qb, const short* __restrict__ Kb,
    const short* __restrict__ Vt, short* __restrict__ Ob) {
    __shared__ short sK[2][32 * HD];   // 4KB x2
    __shared__ short sV[2][HD * 32];   // 4KB x2

    const int t = threadIdx.x;
    const int lane = t & 63, wid = t >> 6;
    const int l31 = lane & 31, hi = lane >> 5;

    const int p = blockIdx.x;                        // 0..767
    const int bh = (p & 7) * 12 + ((p >> 3) >> 3);
    const int qblk = (p >> 3) & 7;
    const int q0 = qblk * 128 + wid * 32;

    const short* Qp = Qb + (size_t)bh * (SEQ * HD);
    const short* Kp = Kb + (size_t)bh * (SEQ * HD);
    const short* Vp = Vt + (size_t)bh * (HD * SEQ);

    // Q fragments (B-operand: col=q=l31, k-dim=d=(hi*8+j) per 16-d slice)
    bf16x8 qf[4];
    #pragma unroll
    for (int ds = 0; ds < 4; ++ds)
        qf[ds] = *(const bf16x8*)&Qp[(size_t)(q0 + l31) * HD + ds * 16 + hi * 8];

    f32x16 o0 = {}, o1 = {};
    float mr = -1e30f, lsum = 0.f;

    // staging indices (wave-uniform LDS base + lane-linear 16B slots)
    const int kr = wid * 8 + (lane >> 3), kg = lane & 7;    // K row, 16B group
    const int vr = wid * 16 + (lane >> 2), vg = lane & 3;   // V row, 16B group

    int cur = 0;
    async_cp16(Kp + (size_t)kr * HD + 8 * (kg ^ (kr & 7)), &sK[0][wid * 512]);
    async_cp16(Vp + (size_t)vr * SEQ + 8 * (vg ^ ((vr >> 1) & 3)), &sV[0][wid * 512]);
    __syncthreads();

    for (int kb = 0; kb < SEQ; kb += 32) {
        if (kb + 32 < SEQ) {
            async_cp16(Kp + (size_t)(kb + 32 + kr) * HD + 8 * (kg ^ (kr & 7)),
                       &sK[cur ^ 1][wid * 512]);
            async_cp16(Vp + (size_t)vr * SEQ + (kb + 32) + 8 * (vg ^ ((vr >> 1) & 3)),
                       &sV[cur ^ 1][wid * 512]);
        }
        // QK^T (swapped): st = S^T tile, 4 chained d-slices
        f32x16 st = {};
        #pragma unroll
        for (int ds = 0; ds < 4; ++ds) {
            bf16x8 kf = *(const bf16x8*)&sK[cur][l31 * HD + 8 * ((ds * 2 + hi) ^ (l31 & 7))];
            st = __builtin_amdgcn_mfma_f32_32x32x16_bf16(kf, qf[ds], st, 0, 0, 0);
        }
        // per-q (per-lane) softmax over this 32-key tile
        float tmax = st[0];
        #pragma unroll
        for (int i = 1; i < 16; ++i) tmax = fmaxf(tmax, st[i]);
        tmax = fmaxf(tmax, __shfl_xor(tmax, 32));
        if (!__all(tmax <= mr + 8.0f)) {           // defer-max: rescale rarely
            float mn = fmaxf(mr, tmax);
            float sc = __expf(mr - mn);
            mr = mn;
            lsum *= sc;
            #pragma unroll
            for (int i = 0; i < 16; ++i) { o0[i] *= sc; o1[i] *= sc; }
        }
        float ts = 0.f;
        #pragma unroll
        for (int i = 0; i < 16; ++i) {
            float pv = __expf(st[i] - mr);
            st[i] = pv;
            ts += pv;
        }
        lsum += ts + __shfl_xor(ts, 32);
        // pack P^T B-frags: cvt_pk pairs + permlane32_swap (one per word pair)
        bf16x8 pf[2];
        #pragma unroll
        for (int kc = 0; kc < 2; ++kc) {
            const int b0 = kc * 8;
            unsigned w0, w1, w2, w3;
            asm("v_cvt_pk_bf16_f32 %0, %1, %2" : "=v"(w0) : "v"(st[b0 + 0]), "v"(st[b0 + 1]));
            asm("v_cvt_pk_bf16_f32 %0, %1, %2" : "=v"(w1) : "v"(st[b0 + 2]), "v"(st[b0 + 3]));
            asm("v_cvt_pk_bf16_f32 %0, %1, %2" : "=v"(w2) : "v"(st[b0 + 4]), "v"(st[b0 + 5]));
            asm("v_cvt_pk_bf16_f32 %0, %1, %2" : "=v"(w3) : "v"(st[b0 + 6]), "v"(st[b0 + 7]));
            asm("v_permlane32_swap_b32 %0, %1" : "+v"(w0), "+v"(w2));
            asm("v_permlane32_swap_b32 %0, %1" : "+v"(w1), "+v"(w3));
            union { unsigned u[4]; bf16x8 v; } pk;
            pk.u[0] = w0; pk.u[1] = w1; pk.u[2] = w2; pk.u[3] = w3;
            pf[kc] = pk.v;
        }
        // PV: O^T += V^T . P^T  (A row = d, k-dim = key)
        #pragma unroll
        for (int kc = 0; kc < 2; ++kc) {
            bf16x8 vf0 = *(const bf16x8*)&sV[cur][l31 * 32 +
                             8 * ((kc * 2 + hi) ^ ((l31 >> 1) & 3))];
            o0 = __builtin_amdgcn_mfma_f32_32x32x16_bf16(vf0, pf[kc], o0, 0, 0, 0);
            const int r1 = l31 + 32;
            bf16x8 vf1 = *(const bf16x8*)&sV[cur][r1 * 32 +
                             8 * ((kc * 2 + hi) ^ ((r1 >> 1) & 3))];
            o1 = __builtin_amdgcn_mfma_f32_32x32x16_bf16(vf1, pf[kc], o1, 0, 0, 0);
        }
        __syncthreads();
        cur ^= 1;
    }

    // epilogue: lane holds O[q][*] for q = q0+l31; d = (reg&3)+8*(reg>>2)+4*hi
    const int b = bh / NH, h = bh % NH;
    const float inv = 1.0f / lsum;
    short* orow = Ob + (size_t)(b * SEQ + q0 + l31) * E_DIM + h * HD;
    #pragma unroll
    for (int qi = 0; qi < 4; ++qi) {
        s16x4 pk0, pk1;
        #pragma unroll
        for (int r = 0; r < 4; ++r) {
            pk0[r] = f2b(o0[qi * 4 + r] * inv);
            pk1[r] = f2b(o1[qi * 4 + r] * inv);
        }
        *(s16x4*)&orow[qi * 8 + hi * 4]      = pk0;
        *(s16x4*)&orow[32 + qi * 8 + hi * 4] = pk1;
    }
}

// ---------------- launch ----------------

extern "C" void kernel_launch(void* const* d_in, const int* in_sizes, int n_in,
                              void* d_out, int out_size, void* d_ws, size_t ws_size,
                              hipStream_t stream) {
    const float* q   = (const float*)d_in[0];
    const float* k   = (const float*)d_in[1];
    const float* v   = (const float*)d_in[2];
    const float* ipw = (const float*)d_in[3];   // (2304, 768)
    const float* ipb = (const float*)d_in[4];   // (2304,)
    const float* ow  = (const float*)d_in[5];   // (768, 768)
    const float* ob  = (const float*)d_in[6];   // (768,)
    const float* la  = (const float*)d_in[7];   // (16, 768)
    const float* lb  = (const float*)d_in[8];   // (2304, 16)
    float* out = (float*)d_out;

    short* qb   = (short*)d_ws;                                   // 3 * 6291456 (Obf)
    short* weff = qb + (size_t)3 * M_DIM * E_DIM;                 // 1769472
    short* oww  = weff + (size_t)2304 * E_DIM;                    // 589824
    short* Qbf  = oww + (size_t)E_DIM * E_DIM;                    // 6291456
    short* Kbf  = Qbf + (size_t)M_DIM * E_DIM;                    // 6291456
    short* Vtb  = Kbf + (size_t)M_DIM * E_DIM;                    // 6291456
    short* Obf  = qb;

    prep_w_kernel<<<2304, 256, 0, stream>>>(ipw, la, lb, ow, weff, oww);
    gemm_bt<0><<<dim3(64, 6, 3), 256, 0, stream>>>(q, k, v, nullptr, weff, ipb,
                                                   Qbf, Kbf, Vtb, nullptr);
    attn_kernel<<<768, 256, 0, stream>>>(Qbf, Kbf, Vtb, Obf);
    gemm_bt<1><<<dim3(64, 6, 1), 256, 0, stream>>>(nullptr, nullptr, nullptr, Obf,
                                                   oww, ob, nullptr, nullptr, nullptr, out);
}

// Round 7
// 241.669 us; speedup vs baseline: 1.1653x; 1.1653x over previous
//
#include <hip/hip_runtime.h>
#include <hip/hip_bf16.h>

// Problem: B=8, S=1024, E=768, H=12, hd=64, R=16.
// Pipeline:
//   1. cvt q,k,v f32 -> bf16 (qb); prep_w: W_eff=ipw+lb@la -> bf16, out_w -> bf16
//   2. GEMM1: [Q|K|V] = x @ W_eff.T + bias (z=0,1,2), dbuf + counted vmcnt(8)
//      (T3/T4: prefetch stays in flight across barriers). Writes Q*0.125/K as
//      [B,H,S,64] bf16, V transposed [B,H,64,S] bf16.
//   3. flash attention per (b,h): swapped-QK^T 32x32 MFMA, in-register softmax
//      (cvt_pk + permlane32_swap), defer-max, LDS-staged K/V (dbuf, XOR-swz),
//      XCD-locality remap. O -> [B,S,E] bf16 (aliases qb)
//   4. GEMM2: out = O @ out_w.T + out_b -> f32 d_out (same dbuf structure).
// ws requirement: ~80.3 MB.

typedef __attribute__((ext_vector_type(4))) float f32x4;
typedef __attribute__((ext_vector_type(16))) float f32x16;
typedef __attribute__((ext_vector_type(8))) short bf16x8;
typedef __attribute__((ext_vector_type(4))) short s16x4;

#define E_DIM 768
#define NB 8
#define SEQ 1024
#define NH 12
#define HD 64
#define M_DIM (NB * SEQ)          // 8192
#define NKT (E_DIM / 64)          // 12 K-tiles

__device__ __forceinline__ short f2b(float f) {
    union { __hip_bfloat16 h; short s; } u;
    u.h = __float2bfloat16(f);
    return u.s;
}

__device__ __forceinline__ void async_cp16(const void* g, void* l) {
    __builtin_amdgcn_global_load_lds(
        (const __attribute__((address_space(1))) void*)g,
        (__attribute__((address_space(3))) void*)l, 16, 0, 0);
}

// ---------------- conversions / weight prep ----------------

__global__ void cvt_qkv_kernel(const float* __restrict__ q, const float* __restrict__ k,
                               const float* __restrict__ v, short* __restrict__ dst) {
    const float* src = (blockIdx.y == 0) ? q : (blockIdx.y == 1 ? k : v);
    short* out = dst + (size_t)blockIdx.y * (size_t)(M_DIM * E_DIM);
    size_t i = ((size_t)blockIdx.x * 256 + threadIdx.x) * 8;
    float4 a = *(const float4*)(src + i);
    float4 b = *(const float4*)(src + i + 4);
    bf16x8 o;
    o[0] = f2b(a.x); o[1] = f2b(a.y); o[2] = f2b(a.z); o[3] = f2b(a.w);
    o[4] = f2b(b.x); o[5] = f2b(b.y); o[6] = f2b(b.z); o[7] = f2b(b.w);
    *(bf16x8*)(out + i) = o;
}

// blocks 0..1727: W_eff[r][c] = ipw[r][c] + sum_j lb[r][j]*la[j][c] -> bf16
// blocks 1728..2303: out_w f32 -> bf16
__global__ void prep_w_kernel(const float* __restrict__ ipw, const float* __restrict__ la,
                              const float* __restrict__ lb, const float* __restrict__ ow,
                              short* __restrict__ W, short* __restrict__ OW) {
    if (blockIdx.x < 1728) {
        int idx = blockIdx.x * 256 + threadIdx.x;       // 442368 total
        int r = idx / 192;
        int c = (idx % 192) * 4;
        float4 acc = *(const float4*)(ipw + (size_t)r * E_DIM + c);
        #pragma unroll
        for (int j = 0; j < 16; ++j) {
            float bb = lb[r * 16 + j];
            float4 aa = *(const float4*)(la + j * E_DIM + c);
            acc.x += bb * aa.x; acc.y += bb * aa.y; acc.z += bb * aa.z; acc.w += bb * aa.w;
        }
        s16x4 o; o[0] = f2b(acc.x); o[1] = f2b(acc.y); o[2] = f2b(acc.z); o[3] = f2b(acc.w);
        *(s16x4*)(W + (size_t)r * E_DIM + c) = o;
    } else {
        int i = ((blockIdx.x - 1728) * 256 + threadIdx.x) * 4;   // 589824 elems
        float4 a = *(const float4*)(ow + i);
        s16x4 o; o[0] = f2b(a.x); o[1] = f2b(a.y); o[2] = f2b(a.z); o[3] = f2b(a.w);
        *(s16x4*)(OW + i) = o;
    }
}

// ---------------- GEMM (C = A @ B^T + bias), 128x128 tile, BK=64 -------------
// Double-buffered global_load_lds staging with COUNTED vmcnt: each iteration
// prefetches tile kt+1 (8 cp16/thread), then waits vmcnt(8) so only the OLD
// tile's loads must land; prefetch stays in flight across the barrier (T4).
// MODE 0: QKV epilogue by z;  MODE 1: f32 out-proj.
template <int MODE>
__global__ __launch_bounds__(256) void gemm_bt(
    const short* __restrict__ Aall, const short* __restrict__ Ball,
    const float* __restrict__ biasAll,
    short* __restrict__ Qb, short* __restrict__ Kb, short* __restrict__ Vt,
    float* __restrict__ Cout) {
    __shared__ short sA[2][128 * 64];
    __shared__ short sB[2][128 * 64];
    const int z = blockIdx.z;
    const short* Ap = Aall + (size_t)z * (size_t)(M_DIM * E_DIM);
    const short* Bp = Ball + (size_t)z * (size_t)(E_DIM * E_DIM);
    const float* bias = biasAll + z * E_DIM;
    const int tm = blockIdx.x * 128;
    const int tn = blockIdx.y * 128;
    const int t = threadIdx.x;
    const int lane = t & 63, wid = t >> 6;
    const int wr = wid >> 1, wc = wid & 1;
    const int lr = lane & 15, lg = lane >> 4;
    const int srow = lane >> 3;   // staging: row within 8-row chunk
    const int sgrp = lane & 7;    // staging: 16B group within row

    // stage A+B tiles (8 cp16/thread): linear LDS dest, inv-XOR-swz global src
    auto stageAB = [&](short* dA, short* dB, int k0) {
        #pragma unroll
        for (int is = 0; is < 4; ++is) {
            const int rbase = is * 32 + wid * 8;
            const int row = rbase + srow;
            const int gsw = (sgrp ^ (row & 7)) << 3;
            async_cp16(Ap + (size_t)(tm + row) * E_DIM + k0 + gsw, dA + rbase * 64);
            async_cp16(Bp + (size_t)(tn + row) * E_DIM + k0 + gsw, dB + rbase * 64);
        }
    };

    f32x4 acc[4][4] = {};

    stageAB(sA[0], sB[0], 0);
    int cur = 0;
    for (int kt = 0; kt < NKT; ++kt) {
        const bool more = (kt + 1 < NKT);
        if (more) {
            stageAB(sA[cur ^ 1], sB[cur ^ 1], (kt + 1) * 64);
            asm volatile("s_waitcnt vmcnt(8)" ::: "memory");   // old tile landed
        } else {
            asm volatile("s_waitcnt vmcnt(0)" ::: "memory");
        }
        __builtin_amdgcn_s_barrier();    // every wave's share of tile kt in LDS
        #pragma unroll
        for (int kk = 0; kk < 2; ++kk) {
            bf16x8 af[4], bfr[4];
            const int kg = kk * 4 + lg;
            #pragma unroll
            for (int i = 0; i < 4; ++i) {
                const int row = wr * 64 + i * 16 + lr;
                af[i] = *(const bf16x8*)&sA[cur][row * 64 + ((kg ^ (row & 7)) << 3)];
            }
            #pragma unroll
            for (int j = 0; j < 4; ++j) {
                const int col = wc * 64 + j * 16 + lr;
                bfr[j] = *(const bf16x8*)&sB[cur][col * 64 + ((kg ^ (col & 7)) << 3)];
            }
            #pragma unroll
            for (int i = 0; i < 4; ++i)
                #pragma unroll
                for (int j = 0; j < 4; ++j)
                    acc[i][j] = __builtin_amdgcn_mfma_f32_16x16x32_bf16(
                        af[i], bfr[j], acc[i][j], 0, 0, 0);
        }
        __builtin_amdgcn_s_barrier();    // all reads of cur done; safe to restage
        cur ^= 1;
    }

    // epilogue: C row m = lg*4+r within frag, col n = lr
    #pragma unroll
    for (int i = 0; i < 4; ++i) {
        const int m0 = tm + wr * 64 + i * 16 + lg * 4;
        const int b = m0 >> 10;
        const int s0 = m0 & 1023;
        #pragma unroll
        for (int j = 0; j < 4; ++j) {
            const int n = tn + wc * 64 + j * 16 + lr;
            const float bia = bias[n];
            f32x4 a = acc[i][j];
            if (MODE == 1) {
                #pragma unroll
                for (int r = 0; r < 4; ++r)
                    Cout[(size_t)(m0 + r) * E_DIM + n] = a[r] + bia;
            } else {
                const int h = n >> 6, d = n & 63;
                const int bh = b * NH + h;
                if (z == 0) {
                    #pragma unroll
                    for (int r = 0; r < 4; ++r)
                        Qb[((size_t)bh * SEQ + s0 + r) * HD + d] = f2b((a[r] + bia) * 0.125f);
                } else if (z == 1) {
                    #pragma unroll
                    for (int r = 0; r < 4; ++r)
                        Kb[((size_t)bh * SEQ + s0 + r) * HD + d] = f2b(a[r] + bia);
                } else {
                    s16x4 pk;
                    #pragma unroll
                    for (int r = 0; r < 4; ++r) pk[r] = f2b(a[r] + bia);
                    *(s16x4*)&Vt[((size_t)bh * HD + d) * SEQ + s0] = pk;   // V transposed
                }
            }
        }
    }
}

// ---------------- flash attention (swapped QK^T, in-register softmax) -------
// grid 768 1-D; XCD remap: bh = (p&7)*12 + (p>>3)/8, qblk = (p>>3)&7.
// Block = 4 waves; wave owns 32 q rows (q = q0 + lane&31; hi = lane>>5 splits
// the k/d fragment dims). K tile [32 k][64 d], V tile [64 d][32 k] in LDS,
// double-buffered, XOR-swizzled (linear dest + inverse-swz global source).
// S^T = mfma_32x32x16(K, Q^T): q = lane&31, k = (reg&3)+8*(reg>>2)+4*hi.
// P -> B-frag via v_cvt_pk_bf16_f32 + v_permlane32_swap_b32 (no LDS).
// O^T = mfma(V^T, P^T): per-lane scalar m/l; defer-max THR=8.
__global__ __launch_bounds__(256) void attn_kernel(
    const short* __restrict__ Qb, const short* __restrict__ Kb,
    const short* __restrict__ Vt, short* __restrict__ Ob) {
    __shared__ short sK[2][32 * HD];   // 4KB x2
    __shared__ short sV[2][HD * 32];   // 4KB x2

    const int t = threadIdx.x;
    const int lane = t & 63, wid = t >> 6;
    const int l31 = lane & 31, hi = lane >> 5;

    const int p = blockIdx.x;                        // 0..767
    const int bh = (p & 7) * 12 + ((p >> 3) >> 3);
    const int qblk = (p >> 3) & 7;
    const int q0 = qblk * 128 + wid * 32;

    const short* Qp = Qb + (size_t)bh * (SEQ * HD);
    const short* Kp = Kb + (size_t)bh * (SEQ * HD);
    const short* Vp = Vt + (size_t)bh * (HD * SEQ);

    // Q fragments (B-operand: col=q=l31, k-dim=d=(hi*8+j) per 16-d slice)
    bf16x8 qf[4];
    #pragma unroll
    for (int ds = 0; ds < 4; ++ds)
        qf[ds] = *(const bf16x8*)&Qp[(size_t)(q0 + l31) * HD + ds * 16 + hi * 8];

    f32x16 o0 = {}, o1 = {};
    float mr = -1e30f, lsum = 0.f;

    // staging indices (wave-uniform LDS base + lane-linear 16B slots)
    const int kr = wid * 8 + (lane >> 3), kg = lane & 7;    // K row, 16B group
    const int vr = wid * 16 + (lane >> 2), vg = lane & 3;   // V row, 16B group

    int cur = 0;
    async_cp16(Kp + (size_t)kr * HD + 8 * (kg ^ (kr & 7)), &sK[0][wid * 512]);
    async_cp16(Vp + (size_t)vr * SEQ + 8 * (vg ^ ((vr >> 1) & 3)), &sV[0][wid * 512]);
    __syncthreads();

    for (int kb = 0; kb < SEQ; kb += 32) {
        if (kb + 32 < SEQ) {
            async_cp16(Kp + (size_t)(kb + 32 + kr) * HD + 8 * (kg ^ (kr & 7)),
                       &sK[cur ^ 1][wid * 512]);
            async_cp16(Vp + (size_t)vr * SEQ + (kb + 32) + 8 * (vg ^ ((vr >> 1) & 3)),
                       &sV[cur ^ 1][wid * 512]);
        }
        // QK^T (swapped): st = S^T tile, 4 chained d-slices
        f32x16 st = {};
        #pragma unroll
        for (int ds = 0; ds < 4; ++ds) {
            bf16x8 kf = *(const bf16x8*)&sK[cur][l31 * HD + 8 * ((ds * 2 + hi) ^ (l31 & 7))];
            st = __builtin_amdgcn_mfma_f32_32x32x16_bf16(kf, qf[ds], st, 0, 0, 0);
        }
        // per-q (per-lane) softmax over this 32-key tile
        float tmax = st[0];
        #pragma unroll
        for (int i = 1; i < 16; ++i) tmax = fmaxf(tmax, st[i]);
        tmax = fmaxf(tmax, __shfl_xor(tmax, 32));
        if (!__all(tmax <= mr + 8.0f)) {           // defer-max: rescale rarely
            float mn = fmaxf(mr, tmax);
            float sc = __expf(mr - mn);
            mr = mn;
            lsum *= sc;
            #pragma unroll
            for (int i = 0; i < 16; ++i) { o0[i] *= sc; o1[i] *= sc; }
        }
        float ts = 0.f;
        #pragma unroll
        for (int i = 0; i < 16; ++i) {
            float pv = __expf(st[i] - mr);
            st[i] = pv;
            ts += pv;
        }
        lsum += ts + __shfl_xor(ts, 32);
        // pack P^T B-frags: cvt_pk pairs + permlane32_swap (one per word pair)
        bf16x8 pf[2];
        #pragma unroll
        for (int kc = 0; kc < 2; ++kc) {
            const int b0 = kc * 8;
            unsigned w0, w1, w2, w3;
            asm("v_cvt_pk_bf16_f32 %0, %1, %2" : "=v"(w0) : "v"(st[b0 + 0]), "v"(st[b0 + 1]));
            asm("v_cvt_pk_bf16_f32 %0, %1, %2" : "=v"(w1) : "v"(st[b0 + 2]), "v"(st[b0 + 3]));
            asm("v_cvt_pk_bf16_f32 %0, %1, %2" : "=v"(w2) : "v"(st[b0 + 4]), "v"(st[b0 + 5]));
            asm("v_cvt_pk_bf16_f32 %0, %1, %2" : "=v"(w3) : "v"(st[b0 + 6]), "v"(st[b0 + 7]));
            asm("v_permlane32_swap_b32 %0, %1" : "+v"(w0), "+v"(w2));
            asm("v_permlane32_swap_b32 %0, %1" : "+v"(w1), "+v"(w3));
            union { unsigned u[4]; bf16x8 v; } pk;
            pk.u[0] = w0; pk.u[1] = w1; pk.u[2] = w2; pk.u[3] = w3;
            pf[kc] = pk.v;
        }
        // PV: O^T += V^T . P^T  (A row = d, k-dim = key)
        #pragma unroll
        for (int kc = 0; kc < 2; ++kc) {
            bf16x8 vf0 = *(const bf16x8*)&sV[cur][l31 * 32 +
                             8 * ((kc * 2 + hi) ^ ((l31 >> 1) & 3))];
            o0 = __builtin_amdgcn_mfma_f32_32x32x16_bf16(vf0, pf[kc], o0, 0, 0, 0);
            const int r1 = l31 + 32;
            bf16x8 vf1 = *(const bf16x8*)&sV[cur][r1 * 32 +
                             8 * ((kc * 2 + hi) ^ ((r1 >> 1) & 3))];
            o1 = __builtin_amdgcn_mfma_f32_32x32x16_bf16(vf1, pf[kc], o1, 0, 0, 0);
        }
        __syncthreads();
        cur ^= 1;
    }

    // epilogue: lane holds O[q][*] for q = q0+l31; d = (reg&3)+8*(reg>>2)+4*hi
    const int b = bh / NH, h = bh % NH;
    const float inv = 1.0f / lsum;
    short* orow = Ob + (size_t)(b * SEQ + q0 + l31) * E_DIM + h * HD;
    #pragma unroll
    for (int qi = 0; qi < 4; ++qi) {
        s16x4 pk0, pk1;
        #pragma unroll
        for (int r = 0; r < 4; ++r) {
            pk0[r] = f2b(o0[qi * 4 + r] * inv);
            pk1[r] = f2b(o1[qi * 4 + r] * inv);
        }
        *(s16x4*)&orow[qi * 8 + hi * 4]      = pk0;
        *(s16x4*)&orow[32 + qi * 8 + hi * 4] = pk1;
    }
}

// ---------------- launch ----------------

extern "C" void kernel_launch(void* const* d_in, const int* in_sizes, int n_in,
                              void* d_out, int out_size, void* d_ws, size_t ws_size,
                              hipStream_t stream) {
    const float* q   = (const float*)d_in[0];
    const float* k   = (const float*)d_in[1];
    const float* v   = (const float*)d_in[2];
    const float* ipw = (const float*)d_in[3];   // (2304, 768)
    const float* ipb = (const float*)d_in[4];   // (2304,)
    const float* ow  = (const float*)d_in[5];   // (768, 768)
    const float* ob  = (const float*)d_in[6];   // (768,)
    const float* la  = (const float*)d_in[7];   // (16, 768)
    const float* lb  = (const float*)d_in[8];   // (2304, 16)
    float* out = (float*)d_out;

    short* qb   = (short*)d_ws;                                   // 3 * 6291456 (Obf)
    short* weff = qb + (size_t)3 * M_DIM * E_DIM;                 // 1769472
    short* oww  = weff + (size_t)2304 * E_DIM;                    // 589824
    short* Qbf  = oww + (size_t)E_DIM * E_DIM;                    // 6291456
    short* Kbf  = Qbf + (size_t)M_DIM * E_DIM;                    // 6291456
    short* Vtb  = Kbf + (size_t)M_DIM * E_DIM;                    // 6291456
    short* Obf  = qb;  // alias: qb no longer needed after GEMM1

    cvt_qkv_kernel<<<dim3(3072, 3), 256, 0, stream>>>(q, k, v, qb);
    prep_w_kernel<<<2304, 256, 0, stream>>>(ipw, la, lb, ow, weff, oww);
    gemm_bt<0><<<dim3(64, 6, 3), 256, 0, stream>>>(qb, weff, ipb, Qbf, Kbf, Vtb, nullptr);
    attn_kernel<<<768, 256, 0, stream>>>(Qbf, Kbf, Vtb, Obf);
    gemm_bt<1><<<dim3(64, 6, 1), 256, 0, stream>>>(Obf, oww, ob, nullptr, nullptr, nullptr, out);
}